// Round 1
// baseline (652.243 us; speedup 1.0000x reference)
//
#include <hip/hip_runtime.h>

#define EMBED_DIM 128
#define MAX_ATOM_TYPE 119
#define TABLE_ELEMS (MAX_ATOM_TYPE * EMBED_DIM)   // 15232 floats = 59.5 KiB

// out[n][d] = W[d][atom_type[n]] + b[d]
// Strategy: build fused LDS table T[t][d] = W[d][t] + b[d] once per block,
// then grid-stride loop writing one float4 per thread per iteration.
__global__ __launch_bounds__(256) void embed_atom_kernel(
    const int* __restrict__ atom_type,
    const float* __restrict__ W,     // [EMBED_DIM][MAX_ATOM_TYPE] row-major
    const float* __restrict__ bias,  // [EMBED_DIM]
    float* __restrict__ out,         // [N][EMBED_DIM]
    int n_atoms)
{
    __shared__ float table[TABLE_ELEMS];

    // Build table: consecutive i -> consecutive LDS addresses (conflict-free
    // writes). W reads are strided but W is 61 KB — L2-resident after first
    // block touches it.
    for (int i = threadIdx.x; i < TABLE_ELEMS; i += 256) {
        int t = i >> 7;        // i / 128  (table row = atom type)
        int d = i & 127;       // i % 128  (embed dim)
        table[i] = W[d * MAX_ATOM_TYPE + t] + bias[d];
    }
    __syncthreads();

    const float4* tab4 = reinterpret_cast<const float4*>(table);
    float4* out4 = reinterpret_cast<float4*>(out);

    // Each atom row = 128 floats = 32 float4s. Thread handles float4 #pos:
    // atom = pos>>5, d4 = pos&31. Consecutive lanes -> consecutive float4s
    // -> perfectly coalesced 16 B/lane stores (1 KiB per wave store).
    const long long total_f4 = (long long)n_atoms * (EMBED_DIM / 4);
    const long long stride   = (long long)gridDim.x * blockDim.x;

    for (long long pos = (long long)blockIdx.x * blockDim.x + threadIdx.x;
         pos < total_f4; pos += stride) {
        int atom = (int)(pos >> 5);
        int d4   = (int)(pos & 31);
        int t    = atom_type[atom];          // 32 lanes share -> broadcast
        out4[pos] = tab4[t * (EMBED_DIM / 4) + d4];
    }
}

extern "C" void kernel_launch(void* const* d_in, const int* in_sizes, int n_in,
                              void* d_out, int out_size, void* d_ws, size_t ws_size,
                              hipStream_t stream) {
    const int*   atom_type = (const int*)d_in[0];
    const float* W         = (const float*)d_in[1];
    const float* bias      = (const float*)d_in[2];
    float*       out       = (float*)d_out;
    int n_atoms = in_sizes[0];

    // 2048 blocks x 256 threads; each thread does ~64 float4 stores via
    // grid-stride loop — amortizes the LDS table build ~64x per block.
    int blocks = 2048;
    embed_atom_kernel<<<blocks, 256, 0, stream>>>(atom_type, W, bias, out, n_atoms);
}

// Round 3
// 545.627 us; speedup vs baseline: 1.1954x; 1.1954x over previous
//
#include <hip/hip_runtime.h>

#define ED 128                  // embed dim
#define NT 119                  // max atom type
#define TE (NT * ED)            // 15232 floats = 59.5 KiB fused table
#define BLK 1024                // main-kernel block size
#define BATCH 8                 // unrolled independent iterations

typedef float f32x4 __attribute__((ext_vector_type(4)));

// ---------- Kernel A: build fused table T[t][d] = W[d][t] + b[d] (once) ----
__global__ __launch_bounds__(256) void build_table(
    const float* __restrict__ W,    // [ED][NT]
    const float* __restrict__ bias, // [ED]
    float* __restrict__ T)          // [NT][ED]
{
    int i = blockIdx.x * 256 + threadIdx.x;   // i = t*128 + d
    if (i < TE) {
        int t = i >> 7;
        int d = i & 127;
        T[i] = W[d * NT + t] + bias[d];
    }
}

// ---------- Kernel B: gather rows of T, coalesced float4 stores ------------
__global__ __launch_bounds__(BLK) void embed_main(
    const int* __restrict__ atom_type,
    const float* __restrict__ T,    // fused table in global (d_ws)
    float* __restrict__ out,        // [N][ED]
    long long total_f4)             // n_atoms * 32
{
    __shared__ f32x4 tab4[TE / 4];  // 59.5 KiB; 1024-thr blocks -> 2 blk/CU = 32 waves/CU

    // Stage table: contiguous float4 copy — coalesced global reads,
    // conflict-free LDS writes. 3808/1024 -> 4 iterations.
    const f32x4* Tg = reinterpret_cast<const f32x4*>(T);
    for (int i = threadIdx.x; i < TE / 4; i += BLK) tab4[i] = Tg[i];
    __syncthreads();

    f32x4* out4 = reinterpret_cast<f32x4*>(out);
    const long long stride = (long long)gridDim.x * BLK;
    const long long base   = (long long)blockIdx.x * BLK + threadIdx.x;

    // Guard-free batched main loop: BATCH independent {atom load -> LDS read
    // -> nontemporal store} chains per iteration, so the compiler issues all
    // BATCH global loads before any consumer (latency pipelining).
    long long pos = base;
    for (; pos + (BATCH - 1) * stride < total_f4; pos += BATCH * stride) {
        int   t[BATCH];
        f32x4 v[BATCH];
#pragma unroll
        for (int k = 0; k < BATCH; ++k) {
            long long p = pos + (long long)k * stride;
            t[k] = atom_type[(int)(p >> 5)];          // 32 lanes share -> 1 req
        }
#pragma unroll
        for (int k = 0; k < BATCH; ++k) {
            long long p = pos + (long long)k * stride;
            v[k] = tab4[t[k] * 32 + (int)(p & 31)];   // conflict-free b128 read
        }
#pragma unroll
        for (int k = 0; k < BATCH; ++k) {
            long long p = pos + (long long)k * stride;
            __builtin_nontemporal_store(v[k], &out4[p]);
        }
    }
    // Tail (empty when grid exactly covers, but keep it correct)
    for (; pos < total_f4; pos += stride) {
        int t = atom_type[(int)(pos >> 5)];
        __builtin_nontemporal_store(tab4[t * 32 + (int)(pos & 31)], &out4[pos]);
    }
}

// ---------- Fallback (ws too small): in-block build, coalesced + padded ----
#define PAD 132                 // 132 % 32 = 4 -> limited write conflicts
__global__ __launch_bounds__(BLK) void embed_fallback(
    const int* __restrict__ atom_type,
    const float* __restrict__ W,
    const float* __restrict__ bias,
    float* __restrict__ out,
    long long total_f4)
{
    __shared__ __align__(16) float tab[NT * PAD];   // 62832 B

    // Coalesced over W's linear layout: j = d*NT + t
    for (int j = threadIdx.x; j < TE; j += BLK) {
        int d = j / NT;
        int t = j - d * NT;
        tab[t * PAD + d] = W[j] + bias[d];
    }
    __syncthreads();

    f32x4* out4 = reinterpret_cast<f32x4*>(out);
    const long long stride = (long long)gridDim.x * BLK;
    for (long long pos = (long long)blockIdx.x * BLK + threadIdx.x;
         pos < total_f4; pos += stride) {
        int t  = atom_type[(int)(pos >> 5)];
        int d4 = (int)(pos & 31);
        f32x4 v = *reinterpret_cast<const f32x4*>(&tab[t * PAD + d4 * 4]);
        __builtin_nontemporal_store(v, &out4[pos]);
    }
}

extern "C" void kernel_launch(void* const* d_in, const int* in_sizes, int n_in,
                              void* d_out, int out_size, void* d_ws, size_t ws_size,
                              hipStream_t stream) {
    const int*   atom_type = (const int*)d_in[0];
    const float* W         = (const float*)d_in[1];
    const float* bias      = (const float*)d_in[2];
    float*       out       = (float*)d_out;
    int n_atoms = (n_in > 0) ? in_sizes[0] : 0;
    if (n_atoms <= 0) return;

    long long total_f4 = (long long)n_atoms * (ED / 4);   // 33.55M for 1M atoms

    if (ws_size >= (size_t)TE * sizeof(float)) {
        float* T = (float*)d_ws;
        build_table<<<(TE + 255) / 256, 256, 0, stream>>>(W, bias, T);
        // blocks so each thread runs ~16 iterations (2 full BATCH groups)
        long long blocks = (total_f4 + (long long)BLK * 16 - 1) / ((long long)BLK * 16);
        if (blocks < 1) blocks = 1;
        embed_main<<<(int)blocks, BLK, 0, stream>>>(atom_type, T, out, total_f4);
    } else {
        long long blocks = (total_f4 + (long long)BLK * 16 - 1) / ((long long)BLK * 16);
        if (blocks < 1) blocks = 1;
        embed_fallback<<<(int)blocks, BLK, 0, stream>>>(atom_type, W, bias, out, total_f4);
    }
}